// Round 1
// baseline (210.484 us; speedup 1.0000x reference)
//
#include <hip/hip_runtime.h>
#include <hip/hip_bf16.h>
#include <stdint.h>

#define BS 4
#define NS 4096
#define NT 16384
#define CT 128
#define NOUT 256
#define MTOT (BS*NT) // 65536
#define GR 8
#define NC (GR*GR*GR)
#define HCELL 0.125f

typedef __attribute__((ext_vector_type(4))) float floatx4;
typedef __attribute__((ext_vector_type(8))) unsigned short ushortx8;
typedef __attribute__((ext_vector_type(8))) __bf16 bf16x8;

__device__ __forceinline__ unsigned short f2bf(float f) {
  unsigned int u = __builtin_bit_cast(unsigned int, f);
  u += 0x7FFFu + ((u >> 16) & 1u);
  return (unsigned short)(u >> 16);
}
__device__ __forceinline__ float bf2f(unsigned short u) {
  return __builtin_bit_cast(float, ((unsigned int)u) << 16);
}
__device__ __forceinline__ int cell_of(float x) {
  int c = (int)(x * 8.0f);
  return min(7, max(0, c));
}

// ---------------- prep: bucket sources (blk 0-3) + sort targets (blk 4-7) + weight transpose (blk 8+) ----------------
__global__ __launch_bounds__(1024) void prep_kernel(
    const float* __restrict__ xyzs, const float* __restrict__ xyzt,
    const float* __restrict__ w1, const float* __restrict__ w2,
    float4* __restrict__ bsrc, int* __restrict__ soff, float4* __restrict__ stgt,
    unsigned short* __restrict__ w1at, unsigned short* __restrict__ w1bt,
    unsigned short* __restrict__ w2t) {
  int bid = blockIdx.x, tid = threadIdx.x;
  if (bid < 8) {
    __shared__ int cnt[NC];
    __shared__ int scan[NC];
    int b = bid & 3;
    bool isrc = bid < 4;
    int per = isrc ? (NS >> 10) : (NT >> 10);
    const float* in = isrc ? xyzs + (size_t)b * NS * 3 : xyzt + (size_t)b * NT * 3;
    float4* outp = isrc ? bsrc + (size_t)b * NS : stgt + (size_t)b * NT;
    if (tid < NC) cnt[tid] = 0;
    __syncthreads();
    for (int k = 0; k < per; ++k) {
      int p = k * 1024 + tid;
      float x = in[3*p], y = in[3*p+1], z = in[3*p+2];
      int c = (cell_of(z) * GR + cell_of(y)) * GR + cell_of(x);
      atomicAdd(&cnt[c], 1);
    }
    __syncthreads();
    if (tid < NC) scan[tid] = cnt[tid];
    __syncthreads();
    for (int off = 1; off < NC; off <<= 1) {
      int v = (tid < NC && tid >= off) ? scan[tid - off] : 0;
      __syncthreads();
      if (tid < NC) scan[tid] += v;
      __syncthreads();
    }
    if (tid < NC) {
      int excl = scan[tid] - cnt[tid];
      cnt[tid] = excl;
      if (isrc) soff[b * (NC + 1) + tid] = excl;
    }
    if (isrc && tid == 0) soff[b * (NC + 1) + NC] = NS;
    __syncthreads();
    for (int k = 0; k < per; ++k) {
      int p = k * 1024 + tid;
      float x = in[3*p], y = in[3*p+1], z = in[3*p+2];
      int c = (cell_of(z) * GR + cell_of(y)) * GR + cell_of(x);
      int slot = atomicAdd(&cnt[c], 1);
      outp[slot] = make_float4(x, y, z, __int_as_float(p));
    }
  } else {
    int i = (bid - 8) * 1024 + tid;  // i < 65536
    int n = i >> 8, k = i & 255;
    w1at[i] = f2bf(w1[k * NOUT + n]);
    w2t[i]  = f2bf(w2[k * NOUT + n]);
    if (i < 256 * 128) {
      int n2 = i >> 7, k2 = i & 127;
      w1bt[i] = f2bf(w1[(256 + k2) * NOUT + n2]);
    }
  }
}

// ---------------- three_nn (bucketed, exact w/ clearance guard); outputs at SORTED positions ----------------
__device__ __forceinline__ void ins3(float sc, int jj,
    float& d0, float& d1, float& d2, int& i0, int& i1, int& i2) {
  bool l0 = sc < d0, l1 = sc < d1, l2 = sc < d2;
  d2 = l1 ? d1 : (l2 ? sc : d2);
  i2 = l1 ? i1 : (l2 ? jj : i2);
  d1 = l0 ? d0 : (l1 ? sc : d1);
  i1 = l0 ? i0 : (l1 ? jj : i1);
  d0 = l0 ? sc : d0;
  i0 = l0 ? jj : i0;
}

__device__ __forceinline__ void pair_merge(float& d0, float& d1, float& d2,
                                           int& i0, int& i1, int& i2,
                                           int delta, int sub) {
  float e0 = __shfl_xor(d0, delta);
  float e1 = __shfl_xor(d1, delta);
  float e2 = __shfl_xor(d2, delta);
  int   y0 = __shfl_xor(i0, delta);
  int   y1 = __shfl_xor(i1, delta);
  int   y2 = __shfl_xor(i2, delta);
  float a0,a1,a2,b0,b1,b2; int x0,x1,x2,z0,z1,z2;
  if ((sub & delta) == 0) { a0=d0;a1=d1;a2=d2; x0=i0;x1=i1;x2=i2;
                            b0=e0;b1=e1;b2=e2; z0=y0;z1=y1;z2=y2; }
  else                    { a0=e0;a1=e1;a2=e2; x0=y0;x1=y1;x2=y2;
                            b0=d0;b1=d1;b2=d2; z0=i0;z1=i1;z2=i2; }
  bool t = a0 <= b0;
  d0 = t ? a0 : b0; i0 = t ? x0 : z0;
  float na0 = t ? a1 : a0; int nx0 = t ? x1 : x0;
  float na1 = t ? a2 : a1; int nx1 = t ? x2 : x1;
  float nb0 = t ? b0 : b1; int nz0 = t ? z0 : z1;
  float nb1 = t ? b1 : b2; int nz1 = t ? z1 : z2;
  t = na0 <= nb0;
  d1 = t ? na0 : nb0; i1 = t ? nx0 : nz0;
  float ma0 = t ? na1 : na0; int mx0 = t ? nx1 : nx0;
  float mb0 = t ? nb0 : nb1; int mz0 = t ? nz0 : nz1;
  t = ma0 <= mb0;
  d2 = t ? ma0 : mb0; i2 = t ? mx0 : mz0;
}

__global__ __launch_bounds__(256) void nn_kernel(const float4* __restrict__ stgt,
    const float4* __restrict__ bsrc, const int* __restrict__ soff,
    int* __restrict__ idx_out, float* __restrict__ w_out) {
  __shared__ float4 s_src[NS];
  __shared__ int s_off[NC + 1];
  int tid = threadIdx.x;
  int b = blockIdx.x >> 7;
  int tseg = blockIdx.x & 127;
  for (int i = tid; i < NS; i += 256) s_src[i] = bsrc[(size_t)b * NS + i];
  for (int i = tid; i < NC + 1; i += 256) s_off[i] = soff[b * (NC + 1) + i];
  __syncthreads();
  int tpair = tid >> 1, half = tid & 1;
  float4 tg = stgt[(size_t)b * NT + tseg * 128 + tpair];
  float tx = tg.x, ty = tg.y, tz = tg.z;
  int cx = cell_of(tx), cy = cell_of(ty), cz = cell_of(tz);
  int wx = min(max(cx, 1), 6) - 1;
  int wy = min(max(cy, 1), 6) - 1;
  int wz = min(max(cz, 1), 6) - 1;
  float d0 = 1e30f, d1 = 1e30f, d2 = 1e30f;
  int i0 = 0, i1 = 0, i2 = 0;
  for (int r = half; r < 9; r += 2) {
    int ez = wz + r / 3, ey = wy + r % 3;
    int rowc = (ez * GR + ey) * GR + wx;
    int lo = s_off[rowc], hi = s_off[rowc + 3];
    for (int p = lo; p < hi; ++p) {
      float4 s = s_src[p];
      float dx = tx - s.x, dy = ty - s.y, dz = tz - s.z;
      float q = dx*dx + dy*dy + dz*dz;
      ins3(q, __float_as_int(s.w), d0, d1, d2, i0, i1, i2);
    }
  }
  pair_merge(d0, d1, d2, i0, i1, i2, 1, half);
  float clx = fminf(wx > 0 ? tx - wx * HCELL : 1e30f,
                    wx + 3 < GR ? (wx + 3) * HCELL - tx : 1e30f);
  float cly = fminf(wy > 0 ? ty - wy * HCELL : 1e30f,
                    wy + 3 < GR ? (wy + 3) * HCELL - ty : 1e30f);
  float clz = fminf(wz > 0 ? tz - wz * HCELL : 1e30f,
                    wz + 3 < GR ? (wz + 3) * HCELL - tz : 1e30f);
  float cl = fminf(clx, fminf(cly, clz));
  bool bad = d2 > cl * cl;
  if (__any(bad)) {
    if (bad) {
      d0 = d1 = d2 = 1e30f; i0 = i1 = i2 = 0;
      for (int p = half; p < NS; p += 2) {
        float4 s = s_src[p];
        float dx = tx - s.x, dy = ty - s.y, dz = tz - s.z;
        float q = dx*dx + dy*dy + dz*dz;
        ins3(q, __float_as_int(s.w), d0, d1, d2, i0, i1, i2);
      }
    }
    pair_merge(d0, d1, d2, i0, i1, i2, 1, half);
  }
  if (half == 0) {
    float r0 = fmaxf(sqrtf(d0), 1e-10f);
    float r1 = fmaxf(sqrtf(d1), 1e-10f);
    float r2 = fmaxf(sqrtf(d2), 1e-10f);
    float v0 = 1.f/r0, v1 = 1.f/r1, v2 = 1.f/r2;
    float sc = 1.f / ((v0 + v1 + v2) * (1.f + 1e-6f));
    // write at SORTED position (fused_mlp consumes sorted order)
    size_t o = ((size_t)b * NT + tseg * 128 + tpair) * 3;
    idx_out[o] = i0; idx_out[o+1] = i1; idx_out[o+2] = i2;
    w_out[o] = v0*sc; w_out[o+1] = v1*sc; w_out[o+2] = v2*sc;
  }
}

// ---------------- G = fs @ W1a  (bf16 out, no relu) ----------------
// 32-row blocks, full K=256 staged once (single barrier), B-frags direct from
// L2-resident w1at. LDS 16.9 KB -> 8 blocks/CU (wave-capped); grid 512 = 2/CU work.
__global__ __launch_bounds__(256) void gemm_g(const float* __restrict__ fs,
    const unsigned short* __restrict__ w1at, unsigned short* __restrict__ G) {
  constexpr int LDT = 264;  // 256 + 8 pad: row stride 132 dwords -> 2-way (free)
  __shared__ __attribute__((aligned(16))) unsigned short sA[32 * LDT];
  int tid = threadIdx.x;
  int m0 = blockIdx.x * 32;
  int wave = tid >> 6, lane = tid & 63;
  int wn = wave * 64;
  int fr = lane & 15, quad = lane >> 4;
  // stage A: 32 rows x 256 cols f32->bf16, 1024 x8-units, 4/thread, coalesced
  #pragma unroll
  for (int i = 0; i < 4; ++i) {
    int u = tid + 256 * i;
    int r = u >> 5, k8 = (u & 31) * 8;
    const float* src = fs + (size_t)(m0 + r) * 256 + k8;
    float4 f0 = *(const float4*)src;
    float4 f1 = *(const float4*)(src + 4);
    ushortx8 o;
    o[0]=f2bf(f0.x); o[1]=f2bf(f0.y); o[2]=f2bf(f0.z); o[3]=f2bf(f0.w);
    o[4]=f2bf(f1.x); o[5]=f2bf(f1.y); o[6]=f2bf(f1.z); o[7]=f2bf(f1.w);
    *(ushortx8*)&sA[r * LDT + k8] = o;
  }
  __syncthreads();
  floatx4 zero = {0.f, 0.f, 0.f, 0.f};
  floatx4 acc[2][4];
  #pragma unroll
  for (int i = 0; i < 2; ++i)
    #pragma unroll
    for (int j = 0; j < 4; ++j) acc[i][j] = zero;
  #pragma unroll
  for (int kk = 0; kk < 256; kk += 32) {
    bf16x8 af[2], bfr[4];
    #pragma unroll
    for (int mi = 0; mi < 2; ++mi)
      af[mi] = __builtin_bit_cast(bf16x8,
          *(const ushortx8*)&sA[(mi*16 + fr)*LDT + kk + quad*8]);
    #pragma unroll
    for (int ni = 0; ni < 4; ++ni)
      bfr[ni] = __builtin_bit_cast(bf16x8,
          *(const ushortx8*)(w1at + (size_t)(wn + ni*16 + fr) * 256 + kk + quad*8));
    #pragma unroll
    for (int mi = 0; mi < 2; ++mi)
      #pragma unroll
      for (int ni = 0; ni < 4; ++ni)
        acc[mi][ni] = __builtin_amdgcn_mfma_f32_16x16x32_bf16(
            af[mi], bfr[ni], acc[mi][ni], 0, 0, 0);
  }
  #pragma unroll
  for (int mi = 0; mi < 2; ++mi)
    #pragma unroll
    for (int ni = 0; ni < 4; ++ni)
      #pragma unroll
      for (int r = 0; r < 4; ++r) {
        int grow = m0 + mi*16 + quad*4 + r;
        int gcol = wn + ni*16 + fr;
        G[(size_t)grow * 256 + gcol] = f2bf(acc[mi][ni][r]);
      }
}

// ---------------- fused: out[orig] = relu(relu(interp + ft[orig]@W1b) @ W2) ----------------
// 32-row blocks: LDS = sI 32x264 (16.9 KB) + sF 32x136 (8.7 KB) = 25.6 KB
// -> 6 blocks/CU resident (24 waves, 75% occ ceiling); grid 2048 = 8 blocks/CU work.
// Numerics identical to 64-row version (same K order, same fragment math).
__global__ __launch_bounds__(256, 6) void fused_mlp(const float* __restrict__ ft,
    const unsigned short* __restrict__ G, const int* __restrict__ idxb,
    const float* __restrict__ wgtb, const float4* __restrict__ stgt,
    const unsigned short* __restrict__ w1bt, const unsigned short* __restrict__ w2t,
    float* __restrict__ out) {
  constexpr int LDI = 264;
  constexpr int LDF = 136;
  __shared__ __attribute__((aligned(16))) unsigned short sI[32 * LDI];
  __shared__ __attribute__((aligned(16))) unsigned short sF[32 * LDF];
  int tid = threadIdx.x;
  int row0 = blockIdx.x * 32;   // global sorted row
  int b = row0 >> 14;
  const float4* st = stgt + ((size_t)b << 14) + (row0 & (NT - 1));
  const float* ftb = ft + (size_t)b * NT * CT;
  float* outb = out + (size_t)b * NT * NOUT;
  int wave = tid >> 6, lane = tid & 63;
  int wn = wave * 64;
  int fr = lane & 15, quad = lane >> 4;

  // ---- interp tile into sI (bf16); idx/wgt are at sorted positions
  {
    int r = tid >> 3, seg = tid & 7;          // 8 threads/row, 32 cols each
    const int* ip = idxb + (size_t)(row0 + r) * 3;
    const float* wp = wgtb + (size_t)(row0 + r) * 3;
    int g0i = ip[0], g1i = ip[1], g2i = ip[2];
    float w0 = wp[0], w1v = wp[1], w2v = wp[2];
    const unsigned short* Gb = G + ((size_t)b << 20);
    const unsigned short* g0 = Gb + ((size_t)g0i << 8) + seg * 32;
    const unsigned short* g1 = Gb + ((size_t)g1i << 8) + seg * 32;
    const unsigned short* g2 = Gb + ((size_t)g2i << 8) + seg * 32;
    #pragma unroll
    for (int j = 0; j < 4; ++j) {
      ushortx8 a = *(const ushortx8*)(g0 + j*8);
      ushortx8 c = *(const ushortx8*)(g1 + j*8);
      ushortx8 e = *(const ushortx8*)(g2 + j*8);
      ushortx8 o;
      #pragma unroll
      for (int q = 0; q < 8; ++q)
        o[q] = f2bf(w0*bf2f(a[q]) + w1v*bf2f(c[q]) + w2v*bf2f(e[q]));
      *(ushortx8*)&sI[r * LDI + seg * 32 + j * 8] = o;
    }
  }
  // ---- full ft tile (32x128) fp32->bf16: 512 x8-units, 2/thread; rows gathered via orig
  #pragma unroll
  for (int i = 0; i < 2; ++i) {
    int u = tid + 256 * i;
    int r = u >> 4, k8 = (u & 15) * 8;
    int orig = __float_as_int(st[r].w);
    const float* src = ftb + (size_t)orig * CT + k8;
    float4 f0 = *(const float4*)src;
    float4 f1 = *(const float4*)(src + 4);
    ushortx8 o;
    o[0]=f2bf(f0.x); o[1]=f2bf(f0.y); o[2]=f2bf(f0.z); o[3]=f2bf(f0.w);
    o[4]=f2bf(f1.x); o[5]=f2bf(f1.y); o[6]=f2bf(f1.z); o[7]=f2bf(f1.w);
    *(ushortx8*)&sF[r * LDF + k8] = o;
  }
  __syncthreads();

  floatx4 zero = {0.f, 0.f, 0.f, 0.f};
  floatx4 acc[2][4];
  #pragma unroll
  for (int i = 0; i < 2; ++i)
    #pragma unroll
    for (int j = 0; j < 4; ++j) acc[i][j] = zero;

  // ---- phase 1: ft @ W1b (K=128), B-frags direct from global
  #pragma unroll
  for (int kk = 0; kk < 128; kk += 32) {
    bf16x8 af[2], bfr[4];
    #pragma unroll
    for (int mi = 0; mi < 2; ++mi)
      af[mi] = __builtin_bit_cast(bf16x8,
          *(const ushortx8*)&sF[(mi*16 + fr)*LDF + kk + quad*8]);
    #pragma unroll
    for (int ni = 0; ni < 4; ++ni)
      bfr[ni] = __builtin_bit_cast(bf16x8,
          *(const ushortx8*)(w1bt + (size_t)(wn + ni*16 + fr) * CT + kk + quad*8));
    #pragma unroll
    for (int mi = 0; mi < 2; ++mi)
      #pragma unroll
      for (int ni = 0; ni < 4; ++ni)
        acc[mi][ni] = __builtin_amdgcn_mfma_f32_16x16x32_bf16(
            af[mi], bfr[ni], acc[mi][ni], 0, 0, 0);
  }

  // ---- phase-1 epilogue: T = relu(acc + interp) bf16, in-place in sI (own cells)
  #pragma unroll
  for (int mi = 0; mi < 2; ++mi)
    #pragma unroll
    for (int ni = 0; ni < 4; ++ni)
      #pragma unroll
      for (int r = 0; r < 4; ++r) {
        int lr = mi*16 + quad*4 + r;
        int lc = wn + ni*16 + fr;
        float v = acc[mi][ni][r] + bf2f(sI[lr * LDI + lc]);
        sI[lr * LDI + lc] = f2bf(fmaxf(v, 0.f));
      }
  __syncthreads();

  // ---- phase 2: T @ W2 (K=256), no barriers
  #pragma unroll
  for (int i = 0; i < 2; ++i)
    #pragma unroll
    for (int j = 0; j < 4; ++j) acc[i][j] = zero;
  #pragma unroll
  for (int kk = 0; kk < 256; kk += 32) {
    bf16x8 af[2], bfr[4];
    #pragma unroll
    for (int mi = 0; mi < 2; ++mi)
      af[mi] = __builtin_bit_cast(bf16x8,
          *(const ushortx8*)&sI[(mi*16 + fr)*LDI + kk + quad*8]);
    #pragma unroll
    for (int ni = 0; ni < 4; ++ni)
      bfr[ni] = __builtin_bit_cast(bf16x8,
          *(const ushortx8*)(w2t + (size_t)(wn + ni*16 + fr) * NOUT + kk + quad*8));
    #pragma unroll
    for (int mi = 0; mi < 2; ++mi)
      #pragma unroll
      for (int ni = 0; ni < 4; ++ni)
        acc[mi][ni] = __builtin_amdgcn_mfma_f32_16x16x32_bf16(
            af[mi], bfr[ni], acc[mi][ni], 0, 0, 0);
  }
  // ---- out epilogue: scatter rows back to original positions
  #pragma unroll
  for (int mi = 0; mi < 2; ++mi)
    #pragma unroll
    for (int r = 0; r < 4; ++r) {
      int lr = mi*16 + quad*4 + r;
      int orig = __float_as_int(st[lr].w);
      float* orow = outb + (size_t)orig * NOUT;
      #pragma unroll
      for (int ni = 0; ni < 4; ++ni)
        orow[wn + ni*16 + fr] = fmaxf(acc[mi][ni][r], 0.f);
    }
}

extern "C" void kernel_launch(void* const* d_in, const int* in_sizes, int n_in,
                              void* d_out, int out_size, void* d_ws, size_t ws_size,
                              hipStream_t stream) {
  (void)in_sizes; (void)n_in; (void)out_size; (void)ws_size;
  const float* xyzt = (const float*)d_in[0];
  const float* xyzs = (const float*)d_in[1];
  const float* ft   = (const float*)d_in[2];
  const float* fs   = (const float*)d_in[3];
  const float* w1   = (const float*)d_in[4];
  const float* w2   = (const float*)d_in[5];

  char* p = (char*)d_ws;
  unsigned short* w1at = (unsigned short*)p; p += (size_t)256*256*2;
  unsigned short* w1bt = (unsigned short*)p; p += (size_t)256*128*2;
  unsigned short* w2t  = (unsigned short*)p; p += (size_t)256*256*2;
  int*   idxb = (int*)p;   p += (size_t)MTOT*3*4;
  float* wgtb = (float*)p; p += (size_t)MTOT*3*4;
  unsigned short* G = (unsigned short*)p; p += (size_t)BS*NS*NOUT*2;
  float4* bsrc = (float4*)p; p += (size_t)BS*NS*16;
  float4* stgt = (float4*)p; p += (size_t)BS*NT*16;
  int*    soff = (int*)p;

  hipLaunchKernelGGL(prep_kernel, dim3(8 + 64), dim3(1024), 0, stream,
                     xyzs, xyzt, w1, w2, bsrc, soff, stgt, w1at, w1bt, w2t);
  hipLaunchKernelGGL(nn_kernel, dim3(512), dim3(256), 0, stream, stgt, bsrc, soff, idxb, wgtb);
  hipLaunchKernelGGL(gemm_g, dim3(BS*NS/32), dim3(256), 0, stream, fs, w1at, G);
  hipLaunchKernelGGL(fused_mlp, dim3(MTOT/32), dim3(256), 0, stream,
                     ft, G, idxb, wgtb, stgt, w1bt, w2t, (float*)d_out);
}

// Round 2
// 200.645 us; speedup vs baseline: 1.0490x; 1.0490x over previous
//
#include <hip/hip_runtime.h>
#include <hip/hip_bf16.h>
#include <stdint.h>

#define BS 4
#define NS 4096
#define NT 16384
#define CT 128
#define NOUT 256
#define MTOT (BS*NT) // 65536
#define GR 8
#define NC (GR*GR*GR)
#define HCELL 0.125f

typedef __attribute__((ext_vector_type(4))) float floatx4;
typedef __attribute__((ext_vector_type(8))) unsigned short ushortx8;
typedef __attribute__((ext_vector_type(8))) __bf16 bf16x8;

__device__ __forceinline__ unsigned short f2bf(float f) {
  unsigned int u = __builtin_bit_cast(unsigned int, f);
  u += 0x7FFFu + ((u >> 16) & 1u);
  return (unsigned short)(u >> 16);
}
__device__ __forceinline__ float bf2f(unsigned short u) {
  return __builtin_bit_cast(float, ((unsigned int)u) << 16);
}
__device__ __forceinline__ int cell_of(float x) {
  int c = (int)(x * 8.0f);
  return min(7, max(0, c));
}

// ---------------- prep: bucket sources (blk 0-3) + sort targets (blk 4-7) + weight transpose (blk 8+) ----------------
__global__ __launch_bounds__(1024) void prep_kernel(
    const float* __restrict__ xyzs, const float* __restrict__ xyzt,
    const float* __restrict__ w1, const float* __restrict__ w2,
    float4* __restrict__ bsrc, int* __restrict__ soff, float4* __restrict__ stgt,
    unsigned short* __restrict__ w1at, unsigned short* __restrict__ w1bt,
    unsigned short* __restrict__ w2t) {
  int bid = blockIdx.x, tid = threadIdx.x;
  if (bid < 8) {
    __shared__ int cnt[NC];
    __shared__ int scan[NC];
    int b = bid & 3;
    bool isrc = bid < 4;
    int per = isrc ? (NS >> 10) : (NT >> 10);
    const float* in = isrc ? xyzs + (size_t)b * NS * 3 : xyzt + (size_t)b * NT * 3;
    float4* outp = isrc ? bsrc + (size_t)b * NS : stgt + (size_t)b * NT;
    if (tid < NC) cnt[tid] = 0;
    __syncthreads();
    for (int k = 0; k < per; ++k) {
      int p = k * 1024 + tid;
      float x = in[3*p], y = in[3*p+1], z = in[3*p+2];
      int c = (cell_of(z) * GR + cell_of(y)) * GR + cell_of(x);
      atomicAdd(&cnt[c], 1);
    }
    __syncthreads();
    if (tid < NC) scan[tid] = cnt[tid];
    __syncthreads();
    for (int off = 1; off < NC; off <<= 1) {
      int v = (tid < NC && tid >= off) ? scan[tid - off] : 0;
      __syncthreads();
      if (tid < NC) scan[tid] += v;
      __syncthreads();
    }
    if (tid < NC) {
      int excl = scan[tid] - cnt[tid];
      cnt[tid] = excl;
      if (isrc) soff[b * (NC + 1) + tid] = excl;
    }
    if (isrc && tid == 0) soff[b * (NC + 1) + NC] = NS;
    __syncthreads();
    for (int k = 0; k < per; ++k) {
      int p = k * 1024 + tid;
      float x = in[3*p], y = in[3*p+1], z = in[3*p+2];
      int c = (cell_of(z) * GR + cell_of(y)) * GR + cell_of(x);
      int slot = atomicAdd(&cnt[c], 1);
      outp[slot] = make_float4(x, y, z, __int_as_float(p));
    }
  } else {
    int i = (bid - 8) * 1024 + tid;  // i < 65536
    int n = i >> 8, k = i & 255;
    w1at[i] = f2bf(w1[k * NOUT + n]);
    w2t[i]  = f2bf(w2[k * NOUT + n]);
    if (i < 256 * 128) {
      int n2 = i >> 7, k2 = i & 127;
      w1bt[i] = f2bf(w1[(256 + k2) * NOUT + n2]);
    }
  }
}

// ---------------- three_nn (bucketed, exact w/ clearance guard); outputs at SORTED positions ----------------
__device__ __forceinline__ void ins3(float sc, int jj,
    float& d0, float& d1, float& d2, int& i0, int& i1, int& i2) {
  bool l0 = sc < d0, l1 = sc < d1, l2 = sc < d2;
  d2 = l1 ? d1 : (l2 ? sc : d2);
  i2 = l1 ? i1 : (l2 ? jj : i2);
  d1 = l0 ? d0 : (l1 ? sc : d1);
  i1 = l0 ? i0 : (l1 ? jj : i1);
  d0 = l0 ? sc : d0;
  i0 = l0 ? jj : i0;
}

__device__ __forceinline__ void pair_merge(float& d0, float& d1, float& d2,
                                           int& i0, int& i1, int& i2,
                                           int delta, int sub) {
  float e0 = __shfl_xor(d0, delta);
  float e1 = __shfl_xor(d1, delta);
  float e2 = __shfl_xor(d2, delta);
  int   y0 = __shfl_xor(i0, delta);
  int   y1 = __shfl_xor(i1, delta);
  int   y2 = __shfl_xor(i2, delta);
  float a0,a1,a2,b0,b1,b2; int x0,x1,x2,z0,z1,z2;
  if ((sub & delta) == 0) { a0=d0;a1=d1;a2=d2; x0=i0;x1=i1;x2=i2;
                            b0=e0;b1=e1;b2=e2; z0=y0;z1=y1;z2=y2; }
  else                    { a0=e0;a1=e1;a2=e2; x0=y0;x1=y1;x2=y2;
                            b0=d0;b1=d1;b2=d2; z0=i0;z1=i1;z2=i2; }
  bool t = a0 <= b0;
  d0 = t ? a0 : b0; i0 = t ? x0 : z0;
  float na0 = t ? a1 : a0; int nx0 = t ? x1 : x0;
  float na1 = t ? a2 : a1; int nx1 = t ? x2 : x1;
  float nb0 = t ? b0 : b1; int nz0 = t ? z0 : z1;
  float nb1 = t ? b1 : b2; int nz1 = t ? z1 : z2;
  t = na0 <= nb0;
  d1 = t ? na0 : nb0; i1 = t ? nx0 : nz0;
  float ma0 = t ? na1 : na0; int mx0 = t ? nx1 : nx0;
  float mb0 = t ? nb0 : nb1; int mz0 = t ? nz0 : nz1;
  t = ma0 <= mb0;
  d2 = t ? ma0 : mb0; i2 = t ? mx0 : mz0;
}

__global__ __launch_bounds__(256) void nn_kernel(const float4* __restrict__ stgt,
    const float4* __restrict__ bsrc, const int* __restrict__ soff,
    int* __restrict__ idx_out, float* __restrict__ w_out) {
  __shared__ float4 s_src[NS];
  __shared__ int s_off[NC + 1];
  int tid = threadIdx.x;
  int b = blockIdx.x >> 7;
  int tseg = blockIdx.x & 127;
  for (int i = tid; i < NS; i += 256) s_src[i] = bsrc[(size_t)b * NS + i];
  for (int i = tid; i < NC + 1; i += 256) s_off[i] = soff[b * (NC + 1) + i];
  __syncthreads();
  int tpair = tid >> 1, half = tid & 1;
  float4 tg = stgt[(size_t)b * NT + tseg * 128 + tpair];
  float tx = tg.x, ty = tg.y, tz = tg.z;
  int cx = cell_of(tx), cy = cell_of(ty), cz = cell_of(tz);
  int wx = min(max(cx, 1), 6) - 1;
  int wy = min(max(cy, 1), 6) - 1;
  int wz = min(max(cz, 1), 6) - 1;
  float d0 = 1e30f, d1 = 1e30f, d2 = 1e30f;
  int i0 = 0, i1 = 0, i2 = 0;
  for (int r = half; r < 9; r += 2) {
    int ez = wz + r / 3, ey = wy + r % 3;
    int rowc = (ez * GR + ey) * GR + wx;
    int lo = s_off[rowc], hi = s_off[rowc + 3];
    for (int p = lo; p < hi; ++p) {
      float4 s = s_src[p];
      float dx = tx - s.x, dy = ty - s.y, dz = tz - s.z;
      float q = dx*dx + dy*dy + dz*dz;
      ins3(q, __float_as_int(s.w), d0, d1, d2, i0, i1, i2);
    }
  }
  pair_merge(d0, d1, d2, i0, i1, i2, 1, half);
  float clx = fminf(wx > 0 ? tx - wx * HCELL : 1e30f,
                    wx + 3 < GR ? (wx + 3) * HCELL - tx : 1e30f);
  float cly = fminf(wy > 0 ? ty - wy * HCELL : 1e30f,
                    wy + 3 < GR ? (wy + 3) * HCELL - ty : 1e30f);
  float clz = fminf(wz > 0 ? tz - wz * HCELL : 1e30f,
                    wz + 3 < GR ? (wz + 3) * HCELL - tz : 1e30f);
  float cl = fminf(clx, fminf(cly, clz));
  bool bad = d2 > cl * cl;
  if (__any(bad)) {
    if (bad) {
      d0 = d1 = d2 = 1e30f; i0 = i1 = i2 = 0;
      for (int p = half; p < NS; p += 2) {
        float4 s = s_src[p];
        float dx = tx - s.x, dy = ty - s.y, dz = tz - s.z;
        float q = dx*dx + dy*dy + dz*dz;
        ins3(q, __float_as_int(s.w), d0, d1, d2, i0, i1, i2);
      }
    }
    pair_merge(d0, d1, d2, i0, i1, i2, 1, half);
  }
  if (half == 0) {
    float r0 = fmaxf(sqrtf(d0), 1e-10f);
    float r1 = fmaxf(sqrtf(d1), 1e-10f);
    float r2 = fmaxf(sqrtf(d2), 1e-10f);
    float v0 = 1.f/r0, v1 = 1.f/r1, v2 = 1.f/r2;
    float sc = 1.f / ((v0 + v1 + v2) * (1.f + 1e-6f));
    // write at SORTED position (fused_mlp consumes sorted order)
    size_t o = ((size_t)b * NT + tseg * 128 + tpair) * 3;
    idx_out[o] = i0; idx_out[o+1] = i1; idx_out[o+2] = i2;
    w_out[o] = v0*sc; w_out[o+1] = v1*sc; w_out[o+2] = v2*sc;
  }
}

// ---------------- G = fs @ W1a  (bf16 out, no relu) ----------------
// 32-row blocks, full K=256 staged once (single barrier), B-frags direct from
// L2-resident w1at. No min-waves bound -> compiler keeps full fragment set in regs.
__global__ __launch_bounds__(256) void gemm_g(const float* __restrict__ fs,
    const unsigned short* __restrict__ w1at, unsigned short* __restrict__ G) {
  constexpr int LDT = 264;  // 256 + 8 pad
  __shared__ __attribute__((aligned(16))) unsigned short sA[32 * LDT];
  int tid = threadIdx.x;
  int m0 = blockIdx.x * 32;
  int wave = tid >> 6, lane = tid & 63;
  int wn = wave * 64;
  int fr = lane & 15, quad = lane >> 4;
  // stage A: 32 rows x 256 cols f32->bf16, 1024 x8-units, 4/thread, coalesced
  #pragma unroll
  for (int i = 0; i < 4; ++i) {
    int u = tid + 256 * i;
    int r = u >> 5, k8 = (u & 31) * 8;
    const float* src = fs + (size_t)(m0 + r) * 256 + k8;
    float4 f0 = *(const float4*)src;
    float4 f1 = *(const float4*)(src + 4);
    ushortx8 o;
    o[0]=f2bf(f0.x); o[1]=f2bf(f0.y); o[2]=f2bf(f0.z); o[3]=f2bf(f0.w);
    o[4]=f2bf(f1.x); o[5]=f2bf(f1.y); o[6]=f2bf(f1.z); o[7]=f2bf(f1.w);
    *(ushortx8*)&sA[r * LDT + k8] = o;
  }
  __syncthreads();
  floatx4 zero = {0.f, 0.f, 0.f, 0.f};
  floatx4 acc[2][4];
  #pragma unroll
  for (int i = 0; i < 2; ++i)
    #pragma unroll
    for (int j = 0; j < 4; ++j) acc[i][j] = zero;
  #pragma unroll
  for (int kk = 0; kk < 256; kk += 32) {
    bf16x8 af[2], bfr[4];
    #pragma unroll
    for (int mi = 0; mi < 2; ++mi)
      af[mi] = __builtin_bit_cast(bf16x8,
          *(const ushortx8*)&sA[(mi*16 + fr)*LDT + kk + quad*8]);
    #pragma unroll
    for (int ni = 0; ni < 4; ++ni)
      bfr[ni] = __builtin_bit_cast(bf16x8,
          *(const ushortx8*)(w1at + (size_t)(wn + ni*16 + fr) * 256 + kk + quad*8));
    #pragma unroll
    for (int mi = 0; mi < 2; ++mi)
      #pragma unroll
      for (int ni = 0; ni < 4; ++ni)
        acc[mi][ni] = __builtin_amdgcn_mfma_f32_16x16x32_bf16(
            af[mi], bfr[ni], acc[mi][ni], 0, 0, 0);
  }
  #pragma unroll
  for (int mi = 0; mi < 2; ++mi)
    #pragma unroll
    for (int ni = 0; ni < 4; ++ni)
      #pragma unroll
      for (int r = 0; r < 4; ++r) {
        int grow = m0 + mi*16 + quad*4 + r;
        int gcol = wn + ni*16 + fr;
        G[(size_t)grow * 256 + gcol] = f2bf(acc[mi][ni][r]);
      }
}

// ---------------- fused: out[orig] = relu(relu(interp + ft[orig]@W1b) @ W2) ----------------
// 64-row tile, 512 threads = 8 waves, each wave owns a 32-col output slice
// (acc[4][2]).  LDS 51.2 KB -> 3 blocks/CU = 24 waves/CU (75% ceiling).
// VGPR budget at 6 waves/SIMD = 85; inner working set acc 32 + af 16 + bfr 8
// + addr ~ 70 -> fits WITHOUT the round-1 register starvation (40 VGPR) that
// serialized B-fragment loads.  Numerics identical to round-0 kernel.
__global__ __launch_bounds__(512, 6) void fused_mlp(const float* __restrict__ ft,
    const unsigned short* __restrict__ G, const int* __restrict__ idxb,
    const float* __restrict__ wgtb, const float4* __restrict__ stgt,
    const unsigned short* __restrict__ w1bt, const unsigned short* __restrict__ w2t,
    float* __restrict__ out) {
  constexpr int LDI = 264;
  constexpr int LDF = 136;
  __shared__ __attribute__((aligned(16))) unsigned short sI[64 * LDI];
  __shared__ __attribute__((aligned(16))) unsigned short sF[64 * LDF];
  int tid = threadIdx.x;
  int row0 = blockIdx.x * 64;   // global sorted row
  int b = row0 >> 14;
  const float4* st = stgt + ((size_t)b << 14) + (row0 & (NT - 1));
  const float* ftb = ft + (size_t)b * NT * CT;
  float* outb = out + (size_t)b * NT * NOUT;
  int wave = tid >> 6, lane = tid & 63;
  int wn = wave * 32;                 // 8 waves x 32 cols = 256
  int fr = lane & 15, quad = lane >> 4;

  // ---- interp tile into sI (bf16); 8 threads/row, 32 cols each
  {
    int r = tid >> 3, seg = tid & 7;
    const int* ip = idxb + (size_t)(row0 + r) * 3;
    const float* wp = wgtb + (size_t)(row0 + r) * 3;
    int g0i = ip[0], g1i = ip[1], g2i = ip[2];
    float w0 = wp[0], w1v = wp[1], w2v = wp[2];
    const unsigned short* Gb = G + ((size_t)b << 20);
    const unsigned short* g0 = Gb + ((size_t)g0i << 8) + seg * 32;
    const unsigned short* g1 = Gb + ((size_t)g1i << 8) + seg * 32;
    const unsigned short* g2 = Gb + ((size_t)g2i << 8) + seg * 32;
    #pragma unroll
    for (int j = 0; j < 4; ++j) {
      ushortx8 a = *(const ushortx8*)(g0 + j*8);
      ushortx8 c = *(const ushortx8*)(g1 + j*8);
      ushortx8 e = *(const ushortx8*)(g2 + j*8);
      ushortx8 o;
      #pragma unroll
      for (int q = 0; q < 8; ++q)
        o[q] = f2bf(w0*bf2f(a[q]) + w1v*bf2f(c[q]) + w2v*bf2f(e[q]));
      *(ushortx8*)&sI[r * LDI + seg * 32 + j * 8] = o;
    }
  }
  // ---- full ft tile (64x128) fp32->bf16: 1024 x8-units, 2/thread; rows via orig
  #pragma unroll
  for (int i = 0; i < 2; ++i) {
    int u = tid + 512 * i;
    int r = u >> 4, k8 = (u & 15) * 8;
    int orig = __float_as_int(st[r].w);
    const float* src = ftb + (size_t)orig * CT + k8;
    float4 f0 = *(const float4*)src;
    float4 f1 = *(const float4*)(src + 4);
    ushortx8 o;
    o[0]=f2bf(f0.x); o[1]=f2bf(f0.y); o[2]=f2bf(f0.z); o[3]=f2bf(f0.w);
    o[4]=f2bf(f1.x); o[5]=f2bf(f1.y); o[6]=f2bf(f1.z); o[7]=f2bf(f1.w);
    *(ushortx8*)&sF[r * LDF + k8] = o;
  }
  __syncthreads();

  floatx4 zero = {0.f, 0.f, 0.f, 0.f};
  floatx4 acc[4][2];
  #pragma unroll
  for (int i = 0; i < 4; ++i)
    #pragma unroll
    for (int j = 0; j < 2; ++j) acc[i][j] = zero;

  // ---- phase 1: ft @ W1b (K=128), B-frags direct from global (L2-resident)
  #pragma unroll
  for (int kk = 0; kk < 128; kk += 32) {
    bf16x8 af[4], bfr[2];
    #pragma unroll
    for (int mi = 0; mi < 4; ++mi)
      af[mi] = __builtin_bit_cast(bf16x8,
          *(const ushortx8*)&sF[(mi*16 + fr)*LDF + kk + quad*8]);
    #pragma unroll
    for (int ni = 0; ni < 2; ++ni)
      bfr[ni] = __builtin_bit_cast(bf16x8,
          *(const ushortx8*)(w1bt + (size_t)(wn + ni*16 + fr) * CT + kk + quad*8));
    #pragma unroll
    for (int mi = 0; mi < 4; ++mi)
      #pragma unroll
      for (int ni = 0; ni < 2; ++ni)
        acc[mi][ni] = __builtin_amdgcn_mfma_f32_16x16x32_bf16(
            af[mi], bfr[ni], acc[mi][ni], 0, 0, 0);
  }

  // ---- phase-1 epilogue: T = relu(acc + interp) bf16, in-place in sI (own cells)
  #pragma unroll
  for (int mi = 0; mi < 4; ++mi)
    #pragma unroll
    for (int ni = 0; ni < 2; ++ni)
      #pragma unroll
      for (int r = 0; r < 4; ++r) {
        int lr = mi*16 + quad*4 + r;
        int lc = wn + ni*16 + fr;
        float v = acc[mi][ni][r] + bf2f(sI[lr * LDI + lc]);
        sI[lr * LDI + lc] = f2bf(fmaxf(v, 0.f));
      }
  __syncthreads();

  // ---- phase 2: T @ W2 (K=256), no further barriers
  #pragma unroll
  for (int i = 0; i < 4; ++i)
    #pragma unroll
    for (int j = 0; j < 2; ++j) acc[i][j] = zero;
  #pragma unroll
  for (int kk = 0; kk < 256; kk += 32) {
    bf16x8 af[4], bfr[2];
    #pragma unroll
    for (int mi = 0; mi < 4; ++mi)
      af[mi] = __builtin_bit_cast(bf16x8,
          *(const ushortx8*)&sI[(mi*16 + fr)*LDI + kk + quad*8]);
    #pragma unroll
    for (int ni = 0; ni < 2; ++ni)
      bfr[ni] = __builtin_bit_cast(bf16x8,
          *(const ushortx8*)(w2t + (size_t)(wn + ni*16 + fr) * NOUT + kk + quad*8));
    #pragma unroll
    for (int mi = 0; mi < 4; ++mi)
      #pragma unroll
      for (int ni = 0; ni < 2; ++ni)
        acc[mi][ni] = __builtin_amdgcn_mfma_f32_16x16x32_bf16(
            af[mi], bfr[ni], acc[mi][ni], 0, 0, 0);
  }
  // ---- out epilogue: scatter rows back to original positions
  #pragma unroll
  for (int mi = 0; mi < 4; ++mi)
    #pragma unroll
    for (int r = 0; r < 4; ++r) {
      int lr = mi*16 + quad*4 + r;
      int orig = __float_as_int(st[lr].w);
      float* orow = outb + (size_t)orig * NOUT;
      #pragma unroll
      for (int ni = 0; ni < 2; ++ni)
        orow[wn + ni*16 + fr] = fmaxf(acc[mi][ni][r], 0.f);
    }
}

extern "C" void kernel_launch(void* const* d_in, const int* in_sizes, int n_in,
                              void* d_out, int out_size, void* d_ws, size_t ws_size,
                              hipStream_t stream) {
  (void)in_sizes; (void)n_in; (void)out_size; (void)ws_size;
  const float* xyzt = (const float*)d_in[0];
  const float* xyzs = (const float*)d_in[1];
  const float* ft   = (const float*)d_in[2];
  const float* fs   = (const float*)d_in[3];
  const float* w1   = (const float*)d_in[4];
  const float* w2   = (const float*)d_in[5];

  char* p = (char*)d_ws;
  unsigned short* w1at = (unsigned short*)p; p += (size_t)256*256*2;
  unsigned short* w1bt = (unsigned short*)p; p += (size_t)256*128*2;
  unsigned short* w2t  = (unsigned short*)p; p += (size_t)256*256*2;
  int*   idxb = (int*)p;   p += (size_t)MTOT*3*4;
  float* wgtb = (float*)p; p += (size_t)MTOT*3*4;
  unsigned short* G = (unsigned short*)p; p += (size_t)BS*NS*NOUT*2;
  float4* bsrc = (float4*)p; p += (size_t)BS*NS*16;
  float4* stgt = (float4*)p; p += (size_t)BS*NT*16;
  int*    soff = (int*)p;

  hipLaunchKernelGGL(prep_kernel, dim3(8 + 64), dim3(1024), 0, stream,
                     xyzs, xyzt, w1, w2, bsrc, soff, stgt, w1at, w1bt, w2t);
  hipLaunchKernelGGL(nn_kernel, dim3(512), dim3(256), 0, stream, stgt, bsrc, soff, idxb, wgtb);
  hipLaunchKernelGGL(gemm_g, dim3(BS*NS/32), dim3(256), 0, stream, fs, w1at, G);
  hipLaunchKernelGGL(fused_mlp, dim3(MTOT/64), dim3(512), 0, stream,
                     ft, G, idxb, wgtb, stgt, w1bt, w2t, (float*)d_out);
}

// Round 3
// 194.059 us; speedup vs baseline: 1.0846x; 1.0339x over previous
//
#include <hip/hip_runtime.h>
#include <hip/hip_bf16.h>
#include <stdint.h>

#define BS 4
#define NS 4096
#define NT 16384
#define CT 128
#define NOUT 256
#define MTOT (BS*NT) // 65536
#define GR 8
#define NC (GR*GR*GR)
#define HCELL 0.125f

typedef __attribute__((ext_vector_type(4))) float floatx4;
typedef __attribute__((ext_vector_type(8))) unsigned short ushortx8;
typedef __attribute__((ext_vector_type(8))) __bf16 bf16x8;

__device__ __forceinline__ unsigned short f2bf(float f) {
  unsigned int u = __builtin_bit_cast(unsigned int, f);
  u += 0x7FFFu + ((u >> 16) & 1u);
  return (unsigned short)(u >> 16);
}
__device__ __forceinline__ float bf2f(unsigned short u) {
  return __builtin_bit_cast(float, ((unsigned int)u) << 16);
}
__device__ __forceinline__ int cell_of(float x) {
  int c = (int)(x * 8.0f);
  return min(7, max(0, c));
}

// ---------------- prep: bucket sources (blk 0-3) + sort targets (blk 4-7) + weight transpose (blk 8+) ----------------
__global__ __launch_bounds__(1024) void prep_kernel(
    const float* __restrict__ xyzs, const float* __restrict__ xyzt,
    const float* __restrict__ w1, const float* __restrict__ w2,
    float4* __restrict__ bsrc, int* __restrict__ soff, float4* __restrict__ stgt,
    unsigned short* __restrict__ w1at, unsigned short* __restrict__ w1bt,
    unsigned short* __restrict__ w2t) {
  int bid = blockIdx.x, tid = threadIdx.x;
  if (bid < 8) {
    __shared__ int cnt[NC];
    __shared__ int scan[NC];
    int b = bid & 3;
    bool isrc = bid < 4;
    int per = isrc ? (NS >> 10) : (NT >> 10);
    const float* in = isrc ? xyzs + (size_t)b * NS * 3 : xyzt + (size_t)b * NT * 3;
    float4* outp = isrc ? bsrc + (size_t)b * NS : stgt + (size_t)b * NT;
    if (tid < NC) cnt[tid] = 0;
    __syncthreads();
    for (int k = 0; k < per; ++k) {
      int p = k * 1024 + tid;
      float x = in[3*p], y = in[3*p+1], z = in[3*p+2];
      int c = (cell_of(z) * GR + cell_of(y)) * GR + cell_of(x);
      atomicAdd(&cnt[c], 1);
    }
    __syncthreads();
    if (tid < NC) scan[tid] = cnt[tid];
    __syncthreads();
    for (int off = 1; off < NC; off <<= 1) {
      int v = (tid < NC && tid >= off) ? scan[tid - off] : 0;
      __syncthreads();
      if (tid < NC) scan[tid] += v;
      __syncthreads();
    }
    if (tid < NC) {
      int excl = scan[tid] - cnt[tid];
      cnt[tid] = excl;
      if (isrc) soff[b * (NC + 1) + tid] = excl;
    }
    if (isrc && tid == 0) soff[b * (NC + 1) + NC] = NS;
    __syncthreads();
    for (int k = 0; k < per; ++k) {
      int p = k * 1024 + tid;
      float x = in[3*p], y = in[3*p+1], z = in[3*p+2];
      int c = (cell_of(z) * GR + cell_of(y)) * GR + cell_of(x);
      int slot = atomicAdd(&cnt[c], 1);
      outp[slot] = make_float4(x, y, z, __int_as_float(p));
    }
  } else {
    int i = (bid - 8) * 1024 + tid;  // i < 65536
    int n = i >> 8, k = i & 255;
    w1at[i] = f2bf(w1[k * NOUT + n]);
    w2t[i]  = f2bf(w2[k * NOUT + n]);
    if (i < 256 * 128) {
      int n2 = i >> 7, k2 = i & 127;
      w1bt[i] = f2bf(w1[(256 + k2) * NOUT + n2]);
    }
  }
}

// ---------------- three_nn (bucketed, exact w/ clearance guard); outputs at SORTED positions ----------------
__device__ __forceinline__ void ins3(float sc, int jj,
    float& d0, float& d1, float& d2, int& i0, int& i1, int& i2) {
  bool l0 = sc < d0, l1 = sc < d1, l2 = sc < d2;
  d2 = l1 ? d1 : (l2 ? sc : d2);
  i2 = l1 ? i1 : (l2 ? jj : i2);
  d1 = l0 ? d0 : (l1 ? sc : d1);
  i1 = l0 ? i0 : (l1 ? jj : i1);
  d0 = l0 ? sc : d0;
  i0 = l0 ? jj : i0;
}

__device__ __forceinline__ void pair_merge(float& d0, float& d1, float& d2,
                                           int& i0, int& i1, int& i2,
                                           int delta, int sub) {
  float e0 = __shfl_xor(d0, delta);
  float e1 = __shfl_xor(d1, delta);
  float e2 = __shfl_xor(d2, delta);
  int   y0 = __shfl_xor(i0, delta);
  int   y1 = __shfl_xor(i1, delta);
  int   y2 = __shfl_xor(i2, delta);
  float a0,a1,a2,b0,b1,b2; int x0,x1,x2,z0,z1,z2;
  if ((sub & delta) == 0) { a0=d0;a1=d1;a2=d2; x0=i0;x1=i1;x2=i2;
                            b0=e0;b1=e1;b2=e2; z0=y0;z1=y1;z2=y2; }
  else                    { a0=e0;a1=e1;a2=e2; x0=y0;x1=y1;x2=y2;
                            b0=d0;b1=d1;b2=d2; z0=i0;z1=i1;z2=i2; }
  bool t = a0 <= b0;
  d0 = t ? a0 : b0; i0 = t ? x0 : z0;
  float na0 = t ? a1 : a0; int nx0 = t ? x1 : x0;
  float na1 = t ? a2 : a1; int nx1 = t ? x2 : x1;
  float nb0 = t ? b0 : b1; int nz0 = t ? z0 : z1;
  float nb1 = t ? b1 : b2; int nz1 = t ? z1 : z2;
  t = na0 <= nb0;
  d1 = t ? na0 : nb0; i1 = t ? nx0 : nz0;
  float ma0 = t ? na1 : na0; int mx0 = t ? nx1 : nx0;
  float mb0 = t ? nb0 : nb1; int mz0 = t ? nz0 : nz1;
  t = ma0 <= mb0;
  d2 = t ? ma0 : mb0; i2 = t ? mx0 : mz0;
}

__global__ __launch_bounds__(256) void nn_kernel(const float4* __restrict__ stgt,
    const float4* __restrict__ bsrc, const int* __restrict__ soff,
    int* __restrict__ idx_out, float* __restrict__ w_out) {
  __shared__ float4 s_src[NS];
  __shared__ int s_off[NC + 1];
  int tid = threadIdx.x;
  int b = blockIdx.x >> 7;
  int tseg = blockIdx.x & 127;
  for (int i = tid; i < NS; i += 256) s_src[i] = bsrc[(size_t)b * NS + i];
  for (int i = tid; i < NC + 1; i += 256) s_off[i] = soff[b * (NC + 1) + i];
  __syncthreads();
  int tpair = tid >> 1, half = tid & 1;
  float4 tg = stgt[(size_t)b * NT + tseg * 128 + tpair];
  float tx = tg.x, ty = tg.y, tz = tg.z;
  int cx = cell_of(tx), cy = cell_of(ty), cz = cell_of(tz);
  int wx = min(max(cx, 1), 6) - 1;
  int wy = min(max(cy, 1), 6) - 1;
  int wz = min(max(cz, 1), 6) - 1;
  float d0 = 1e30f, d1 = 1e30f, d2 = 1e30f;
  int i0 = 0, i1 = 0, i2 = 0;
  for (int r = half; r < 9; r += 2) {
    int ez = wz + r / 3, ey = wy + r % 3;
    int rowc = (ez * GR + ey) * GR + wx;
    int lo = s_off[rowc], hi = s_off[rowc + 3];
    for (int p = lo; p < hi; ++p) {
      float4 s = s_src[p];
      float dx = tx - s.x, dy = ty - s.y, dz = tz - s.z;
      float q = dx*dx + dy*dy + dz*dz;
      ins3(q, __float_as_int(s.w), d0, d1, d2, i0, i1, i2);
    }
  }
  pair_merge(d0, d1, d2, i0, i1, i2, 1, half);
  float clx = fminf(wx > 0 ? tx - wx * HCELL : 1e30f,
                    wx + 3 < GR ? (wx + 3) * HCELL - tx : 1e30f);
  float cly = fminf(wy > 0 ? ty - wy * HCELL : 1e30f,
                    wy + 3 < GR ? (wy + 3) * HCELL - ty : 1e30f);
  float clz = fminf(wz > 0 ? tz - wz * HCELL : 1e30f,
                    wz + 3 < GR ? (wz + 3) * HCELL - tz : 1e30f);
  float cl = fminf(clx, fminf(cly, clz));
  bool bad = d2 > cl * cl;
  if (__any(bad)) {
    if (bad) {
      d0 = d1 = d2 = 1e30f; i0 = i1 = i2 = 0;
      for (int p = half; p < NS; p += 2) {
        float4 s = s_src[p];
        float dx = tx - s.x, dy = ty - s.y, dz = tz - s.z;
        float q = dx*dx + dy*dy + dz*dz;
        ins3(q, __float_as_int(s.w), d0, d1, d2, i0, i1, i2);
      }
    }
    pair_merge(d0, d1, d2, i0, i1, i2, 1, half);
  }
  if (half == 0) {
    float r0 = fmaxf(sqrtf(d0), 1e-10f);
    float r1 = fmaxf(sqrtf(d1), 1e-10f);
    float r2 = fmaxf(sqrtf(d2), 1e-10f);
    float v0 = 1.f/r0, v1 = 1.f/r1, v2 = 1.f/r2;
    float sc = 1.f / ((v0 + v1 + v2) * (1.f + 1e-6f));
    // write at SORTED position (fused_mlp consumes sorted order)
    size_t o = ((size_t)b * NT + tseg * 128 + tpair) * 3;
    idx_out[o] = i0; idx_out[o+1] = i1; idx_out[o+2] = i2;
    w_out[o] = v0*sc; w_out[o+1] = v1*sc; w_out[o+2] = v2*sc;
  }
}

// ---------------- G = fs @ W1a  (bf16 out, no relu) ----------------
__global__ __launch_bounds__(256) void gemm_g(const float* __restrict__ fs,
    const unsigned short* __restrict__ w1at, unsigned short* __restrict__ G) {
  constexpr int LDT = 264;  // 256 + 8 pad
  __shared__ __attribute__((aligned(16))) unsigned short sA[32 * LDT];
  int tid = threadIdx.x;
  int m0 = blockIdx.x * 32;
  int wave = tid >> 6, lane = tid & 63;
  int wn = wave * 64;
  int fr = lane & 15, quad = lane >> 4;
  // stage A: 32 rows x 256 cols f32->bf16, 1024 x8-units, 4/thread, coalesced
  #pragma unroll
  for (int i = 0; i < 4; ++i) {
    int u = tid + 256 * i;
    int r = u >> 5, k8 = (u & 31) * 8;
    const float* src = fs + (size_t)(m0 + r) * 256 + k8;
    float4 f0 = *(const float4*)src;
    float4 f1 = *(const float4*)(src + 4);
    ushortx8 o;
    o[0]=f2bf(f0.x); o[1]=f2bf(f0.y); o[2]=f2bf(f0.z); o[3]=f2bf(f0.w);
    o[4]=f2bf(f1.x); o[5]=f2bf(f1.y); o[6]=f2bf(f1.z); o[7]=f2bf(f1.w);
    *(ushortx8*)&sA[r * LDT + k8] = o;
  }
  __syncthreads();
  floatx4 zero = {0.f, 0.f, 0.f, 0.f};
  floatx4 acc[2][4];
  #pragma unroll
  for (int i = 0; i < 2; ++i)
    #pragma unroll
    for (int j = 0; j < 4; ++j) acc[i][j] = zero;
  #pragma unroll
  for (int kk = 0; kk < 256; kk += 32) {
    bf16x8 af[2], bfr[4];
    #pragma unroll
    for (int mi = 0; mi < 2; ++mi)
      af[mi] = __builtin_bit_cast(bf16x8,
          *(const ushortx8*)&sA[(mi*16 + fr)*LDT + kk + quad*8]);
    #pragma unroll
    for (int ni = 0; ni < 4; ++ni)
      bfr[ni] = __builtin_bit_cast(bf16x8,
          *(const ushortx8*)(w1at + (size_t)(wn + ni*16 + fr) * 256 + kk + quad*8));
    #pragma unroll
    for (int mi = 0; mi < 2; ++mi)
      #pragma unroll
      for (int ni = 0; ni < 4; ++ni)
        acc[mi][ni] = __builtin_amdgcn_mfma_f32_16x16x32_bf16(
            af[mi], bfr[ni], acc[mi][ni], 0, 0, 0);
  }
  #pragma unroll
  for (int mi = 0; mi < 2; ++mi)
    #pragma unroll
    for (int ni = 0; ni < 4; ++ni)
      #pragma unroll
      for (int r = 0; r < 4; ++r) {
        int grow = m0 + mi*16 + quad*4 + r;
        int gcol = wn + ni*16 + fr;
        G[(size_t)grow * 256 + gcol] = f2bf(acc[mi][ni][r]);
      }
}

// ---------------- fused: out[orig] = relu(relu(interp + ft[orig]@W1b) @ W2) ----------------
// 64-row tile, 512 threads = 8 waves, wave owns a 32-col slice (acc[4][2]).
// KEY CHANGE vs round 2: weight B-fragments are HOISTED into registers for the
// whole phase (wb1[2][4]=32 VGPR at entry; wb2[2][8]=64 VGPR loaded under the
// phase-1 epilogue+barrier).  Round-1/2 counters showed VGPR_Count=40 = acc(32)
// + ONE fragment pair(8): the scheduler had fully serialized load->MFMA.
// launch_bounds(512,4): VGPR budget 128 (peak live ~126); LDS 51.2 KB;
// occupancy 2 blocks/CU (16 waves, 50%).  Numerics bit-identical.
__global__ __launch_bounds__(512, 4) void fused_mlp(const float* __restrict__ ft,
    const unsigned short* __restrict__ G, const int* __restrict__ idxb,
    const float* __restrict__ wgtb, const float4* __restrict__ stgt,
    const unsigned short* __restrict__ w1bt, const unsigned short* __restrict__ w2t,
    float* __restrict__ out) {
  constexpr int LDI = 264;
  constexpr int LDF = 136;
  __shared__ __attribute__((aligned(16))) unsigned short sI[64 * LDI];
  __shared__ __attribute__((aligned(16))) unsigned short sF[64 * LDF];
  int tid = threadIdx.x;
  int row0 = blockIdx.x * 64;   // global sorted row
  int b = row0 >> 14;
  const float4* st = stgt + ((size_t)b << 14) + (row0 & (NT - 1));
  const float* ftb = ft + (size_t)b * NT * CT;
  float* outb = out + (size_t)b * NT * NOUT;
  int wave = tid >> 6, lane = tid & 63;
  int wn = wave * 32;                 // 8 waves x 32 cols = 256
  int fr = lane & 15, quad = lane >> 4;

  // ---- hoist phase-1 weights (w1bt slice) into registers: 2x4 frags = 32 VGPR.
  // Issued first so L2 latency hides under the staging gathers below.
  bf16x8 wb1[2][4];
  #pragma unroll
  for (int ni = 0; ni < 2; ++ni)
    #pragma unroll
    for (int kt = 0; kt < 4; ++kt)
      wb1[ni][kt] = __builtin_bit_cast(bf16x8,
          *(const ushortx8*)(w1bt + (size_t)(wn + ni*16 + fr) * CT + kt*32 + quad*8));

  // ---- interp tile into sI (bf16); 8 threads/row, 32 cols each
  {
    int r = tid >> 3, seg = tid & 7;
    const int* ip = idxb + (size_t)(row0 + r) * 3;
    const float* wp = wgtb + (size_t)(row0 + r) * 3;
    int g0i = ip[0], g1i = ip[1], g2i = ip[2];
    float w0 = wp[0], w1v = wp[1], w2v = wp[2];
    const unsigned short* Gb = G + ((size_t)b << 20);
    const unsigned short* g0 = Gb + ((size_t)g0i << 8) + seg * 32;
    const unsigned short* g1 = Gb + ((size_t)g1i << 8) + seg * 32;
    const unsigned short* g2 = Gb + ((size_t)g2i << 8) + seg * 32;
    #pragma unroll
    for (int j = 0; j < 4; ++j) {
      ushortx8 a = *(const ushortx8*)(g0 + j*8);
      ushortx8 c = *(const ushortx8*)(g1 + j*8);
      ushortx8 e = *(const ushortx8*)(g2 + j*8);
      ushortx8 o;
      #pragma unroll
      for (int q = 0; q < 8; ++q)
        o[q] = f2bf(w0*bf2f(a[q]) + w1v*bf2f(c[q]) + w2v*bf2f(e[q]));
      *(ushortx8*)&sI[r * LDI + seg * 32 + j * 8] = o;
    }
  }
  // ---- full ft tile (64x128) fp32->bf16: 1024 x8-units, 2/thread; rows via orig
  #pragma unroll
  for (int i = 0; i < 2; ++i) {
    int u = tid + 512 * i;
    int r = u >> 4, k8 = (u & 15) * 8;
    int orig = __float_as_int(st[r].w);
    const float* src = ftb + (size_t)orig * CT + k8;
    float4 f0 = *(const float4*)src;
    float4 f1 = *(const float4*)(src + 4);
    ushortx8 o;
    o[0]=f2bf(f0.x); o[1]=f2bf(f0.y); o[2]=f2bf(f0.z); o[3]=f2bf(f0.w);
    o[4]=f2bf(f1.x); o[5]=f2bf(f1.y); o[6]=f2bf(f1.z); o[7]=f2bf(f1.w);
    *(ushortx8*)&sF[r * LDF + k8] = o;
  }
  __syncthreads();

  floatx4 zero = {0.f, 0.f, 0.f, 0.f};
  floatx4 acc[4][2];
  #pragma unroll
  for (int i = 0; i < 4; ++i)
    #pragma unroll
    for (int j = 0; j < 2; ++j) acc[i][j] = zero;

  // ---- phase 1: ft @ W1b (K=128); B already in registers, only A from LDS
  #pragma unroll
  for (int kt = 0; kt < 4; ++kt) {
    bf16x8 af[4];
    #pragma unroll
    for (int mi = 0; mi < 4; ++mi)
      af[mi] = __builtin_bit_cast(bf16x8,
          *(const ushortx8*)&sF[(mi*16 + fr)*LDF + kt*32 + quad*8]);
    #pragma unroll
    for (int mi = 0; mi < 4; ++mi)
      #pragma unroll
      for (int ni = 0; ni < 2; ++ni)
        acc[mi][ni] = __builtin_amdgcn_mfma_f32_16x16x32_bf16(
            af[mi], wb1[ni][kt], acc[mi][ni], 0, 0, 0);
  }

  // ---- hoist phase-2 weights (w2t slice): 2x8 frags = 64 VGPR.
  // L2 latency hides under the epilogue LDS traffic + barrier below.
  bf16x8 wb2[2][8];
  #pragma unroll
  for (int ni = 0; ni < 2; ++ni)
    #pragma unroll
    for (int kt = 0; kt < 8; ++kt)
      wb2[ni][kt] = __builtin_bit_cast(bf16x8,
          *(const ushortx8*)(w2t + (size_t)(wn + ni*16 + fr) * NOUT + kt*32 + quad*8));

  // ---- phase-1 epilogue: T = relu(acc + interp) bf16, in-place in sI (own cells)
  #pragma unroll
  for (int mi = 0; mi < 4; ++mi)
    #pragma unroll
    for (int ni = 0; ni < 2; ++ni)
      #pragma unroll
      for (int r = 0; r < 4; ++r) {
        int lr = mi*16 + quad*4 + r;
        int lc = wn + ni*16 + fr;
        float v = acc[mi][ni][r] + bf2f(sI[lr * LDI + lc]);
        sI[lr * LDI + lc] = f2bf(fmaxf(v, 0.f));
      }
  __syncthreads();

  // ---- phase 2: T @ W2 (K=256); B in registers, A from LDS, no barriers
  #pragma unroll
  for (int i = 0; i < 4; ++i)
    #pragma unroll
    for (int j = 0; j < 2; ++j) acc[i][j] = zero;
  #pragma unroll
  for (int kt = 0; kt < 8; ++kt) {
    bf16x8 af[4];
    #pragma unroll
    for (int mi = 0; mi < 4; ++mi)
      af[mi] = __builtin_bit_cast(bf16x8,
          *(const ushortx8*)&sI[(mi*16 + fr)*LDI + kt*32 + quad*8]);
    #pragma unroll
    for (int mi = 0; mi < 4; ++mi)
      #pragma unroll
      for (int ni = 0; ni < 2; ++ni)
        acc[mi][ni] = __builtin_amdgcn_mfma_f32_16x16x32_bf16(
            af[mi], wb2[ni][kt], acc[mi][ni], 0, 0, 0);
  }
  // ---- out epilogue: scatter rows back to original positions
  #pragma unroll
  for (int mi = 0; mi < 4; ++mi)
    #pragma unroll
    for (int r = 0; r < 4; ++r) {
      int lr = mi*16 + quad*4 + r;
      int orig = __float_as_int(st[lr].w);
      float* orow = outb + (size_t)orig * NOUT;
      #pragma unroll
      for (int ni = 0; ni < 2; ++ni)
        orow[wn + ni*16 + fr] = fmaxf(acc[mi][ni][r], 0.f);
    }
}

extern "C" void kernel_launch(void* const* d_in, const int* in_sizes, int n_in,
                              void* d_out, int out_size, void* d_ws, size_t ws_size,
                              hipStream_t stream) {
  (void)in_sizes; (void)n_in; (void)out_size; (void)ws_size;
  const float* xyzt = (const float*)d_in[0];
  const float* xyzs = (const float*)d_in[1];
  const float* ft   = (const float*)d_in[2];
  const float* fs   = (const float*)d_in[3];
  const float* w1   = (const float*)d_in[4];
  const float* w2   = (const float*)d_in[5];

  char* p = (char*)d_ws;
  unsigned short* w1at = (unsigned short*)p; p += (size_t)256*256*2;
  unsigned short* w1bt = (unsigned short*)p; p += (size_t)256*128*2;
  unsigned short* w2t  = (unsigned short*)p; p += (size_t)256*256*2;
  int*   idxb = (int*)p;   p += (size_t)MTOT*3*4;
  float* wgtb = (float*)p; p += (size_t)MTOT*3*4;
  unsigned short* G = (unsigned short*)p; p += (size_t)BS*NS*NOUT*2;
  float4* bsrc = (float4*)p; p += (size_t)BS*NS*16;
  float4* stgt = (float4*)p; p += (size_t)BS*NT*16;
  int*    soff = (int*)p;

  hipLaunchKernelGGL(prep_kernel, dim3(8 + 64), dim3(1024), 0, stream,
                     xyzs, xyzt, w1, w2, bsrc, soff, stgt, w1at, w1bt, w2t);
  hipLaunchKernelGGL(nn_kernel, dim3(512), dim3(256), 0, stream, stgt, bsrc, soff, idxb, wgtb);
  hipLaunchKernelGGL(gemm_g, dim3(BS*NS/32), dim3(256), 0, stream, fs, w1at, G);
  hipLaunchKernelGGL(fused_mlp, dim3(MTOT/64), dim3(512), 0, stream,
                     ft, G, idxb, wgtb, stgt, w1bt, w2t, (float*)d_out);
}

// Round 4
// 192.964 us; speedup vs baseline: 1.0908x; 1.0057x over previous
//
#include <hip/hip_runtime.h>
#include <hip/hip_bf16.h>
#include <stdint.h>

#define BS 4
#define NS 4096
#define NT 16384
#define CT 128
#define NOUT 256
#define MTOT (BS*NT) // 65536
#define GR 8
#define NC (GR*GR*GR)
#define HCELL 0.125f

typedef __attribute__((ext_vector_type(4))) float floatx4;
typedef __attribute__((ext_vector_type(8))) unsigned short ushortx8;
typedef __attribute__((ext_vector_type(8))) __bf16 bf16x8;

__device__ __forceinline__ unsigned short f2bf(float f) {
  unsigned int u = __builtin_bit_cast(unsigned int, f);
  u += 0x7FFFu + ((u >> 16) & 1u);
  return (unsigned short)(u >> 16);
}
__device__ __forceinline__ float bf2f(unsigned short u) {
  return __builtin_bit_cast(float, ((unsigned int)u) << 16);
}
__device__ __forceinline__ int cell_of(float x) {
  int c = (int)(x * 8.0f);
  return min(7, max(0, c));
}
__device__ __forceinline__ bf16x8 ldb16(const unsigned short* p) {
  return __builtin_bit_cast(bf16x8, *(const ushortx8*)p);
}
__device__ __forceinline__ ushortx8 wsum8(ushortx8 a, ushortx8 c, ushortx8 e,
                                          float w0, float w1v, float w2v) {
  ushortx8 o;
  #pragma unroll
  for (int q = 0; q < 8; ++q)
    o[q] = f2bf(w0*bf2f(a[q]) + w1v*bf2f(c[q]) + w2v*bf2f(e[q]));
  return o;
}

// ---------------- prep: bucket sources (blk 0-3) + sort targets (blk 4-7) + weight transpose (blk 8+) ----------------
__global__ __launch_bounds__(1024) void prep_kernel(
    const float* __restrict__ xyzs, const float* __restrict__ xyzt,
    const float* __restrict__ w1, const float* __restrict__ w2,
    float4* __restrict__ bsrc, int* __restrict__ soff, float4* __restrict__ stgt,
    unsigned short* __restrict__ w1at, unsigned short* __restrict__ w1bt,
    unsigned short* __restrict__ w2t) {
  int bid = blockIdx.x, tid = threadIdx.x;
  if (bid < 8) {
    __shared__ int cnt[NC];
    __shared__ int scan[NC];
    int b = bid & 3;
    bool isrc = bid < 4;
    int per = isrc ? (NS >> 10) : (NT >> 10);
    const float* in = isrc ? xyzs + (size_t)b * NS * 3 : xyzt + (size_t)b * NT * 3;
    float4* outp = isrc ? bsrc + (size_t)b * NS : stgt + (size_t)b * NT;
    if (tid < NC) cnt[tid] = 0;
    __syncthreads();
    for (int k = 0; k < per; ++k) {
      int p = k * 1024 + tid;
      float x = in[3*p], y = in[3*p+1], z = in[3*p+2];
      int c = (cell_of(z) * GR + cell_of(y)) * GR + cell_of(x);
      atomicAdd(&cnt[c], 1);
    }
    __syncthreads();
    if (tid < NC) scan[tid] = cnt[tid];
    __syncthreads();
    for (int off = 1; off < NC; off <<= 1) {
      int v = (tid < NC && tid >= off) ? scan[tid - off] : 0;
      __syncthreads();
      if (tid < NC) scan[tid] += v;
      __syncthreads();
    }
    if (tid < NC) {
      int excl = scan[tid] - cnt[tid];
      cnt[tid] = excl;
      if (isrc) soff[b * (NC + 1) + tid] = excl;
    }
    if (isrc && tid == 0) soff[b * (NC + 1) + NC] = NS;
    __syncthreads();
    for (int k = 0; k < per; ++k) {
      int p = k * 1024 + tid;
      float x = in[3*p], y = in[3*p+1], z = in[3*p+2];
      int c = (cell_of(z) * GR + cell_of(y)) * GR + cell_of(x);
      int slot = atomicAdd(&cnt[c], 1);
      outp[slot] = make_float4(x, y, z, __int_as_float(p));
    }
  } else {
    int i = (bid - 8) * 1024 + tid;  // i < 65536
    int n = i >> 8, k = i & 255;
    w1at[i] = f2bf(w1[k * NOUT + n]);
    w2t[i]  = f2bf(w2[k * NOUT + n]);
    if (i < 256 * 128) {
      int n2 = i >> 7, k2 = i & 127;
      w1bt[i] = f2bf(w1[(256 + k2) * NOUT + n2]);
    }
  }
}

// ---------------- three_nn (bucketed, exact w/ clearance guard); outputs at SORTED positions ----------------
__device__ __forceinline__ void ins3(float sc, int jj,
    float& d0, float& d1, float& d2, int& i0, int& i1, int& i2) {
  bool l0 = sc < d0, l1 = sc < d1, l2 = sc < d2;
  d2 = l1 ? d1 : (l2 ? sc : d2);
  i2 = l1 ? i1 : (l2 ? jj : i2);
  d1 = l0 ? d0 : (l1 ? sc : d1);
  i1 = l0 ? i0 : (l1 ? jj : i1);
  d0 = l0 ? sc : d0;
  i0 = l0 ? jj : i0;
}

__device__ __forceinline__ void pair_merge(float& d0, float& d1, float& d2,
                                           int& i0, int& i1, int& i2,
                                           int delta, int sub) {
  float e0 = __shfl_xor(d0, delta);
  float e1 = __shfl_xor(d1, delta);
  float e2 = __shfl_xor(d2, delta);
  int   y0 = __shfl_xor(i0, delta);
  int   y1 = __shfl_xor(i1, delta);
  int   y2 = __shfl_xor(i2, delta);
  float a0,a1,a2,b0,b1,b2; int x0,x1,x2,z0,z1,z2;
  if ((sub & delta) == 0) { a0=d0;a1=d1;a2=d2; x0=i0;x1=i1;x2=i2;
                            b0=e0;b1=e1;b2=e2; z0=y0;z1=y1;z2=y2; }
  else                    { a0=e0;a1=e1;a2=e2; x0=y0;x1=y1;x2=y2;
                            b0=d0;b1=d1;b2=d2; z0=i0;z1=i1;z2=i2; }
  bool t = a0 <= b0;
  d0 = t ? a0 : b0; i0 = t ? x0 : z0;
  float na0 = t ? a1 : a0; int nx0 = t ? x1 : x0;
  float na1 = t ? a2 : a1; int nx1 = t ? x2 : x1;
  float nb0 = t ? b0 : b1; int nz0 = t ? z0 : z1;
  float nb1 = t ? b1 : b2; int nz1 = t ? z1 : z2;
  t = na0 <= nb0;
  d1 = t ? na0 : nb0; i1 = t ? nx0 : nz0;
  float ma0 = t ? na1 : na0; int mx0 = t ? nx1 : nx0;
  float mb0 = t ? nb0 : nb1; int mz0 = t ? nz0 : nz1;
  t = ma0 <= mb0;
  d2 = t ? ma0 : mb0; i2 = t ? mx0 : mz0;
}

__global__ __launch_bounds__(256) void nn_kernel(const float4* __restrict__ stgt,
    const float4* __restrict__ bsrc, const int* __restrict__ soff,
    int* __restrict__ idx_out, float* __restrict__ w_out) {
  __shared__ float4 s_src[NS];
  __shared__ int s_off[NC + 1];
  int tid = threadIdx.x;
  int b = blockIdx.x >> 7;
  int tseg = blockIdx.x & 127;
  for (int i = tid; i < NS; i += 256) s_src[i] = bsrc[(size_t)b * NS + i];
  for (int i = tid; i < NC + 1; i += 256) s_off[i] = soff[b * (NC + 1) + i];
  __syncthreads();
  int tpair = tid >> 1, half = tid & 1;
  float4 tg = stgt[(size_t)b * NT + tseg * 128 + tpair];
  float tx = tg.x, ty = tg.y, tz = tg.z;
  int cx = cell_of(tx), cy = cell_of(ty), cz = cell_of(tz);
  int wx = min(max(cx, 1), 6) - 1;
  int wy = min(max(cy, 1), 6) - 1;
  int wz = min(max(cz, 1), 6) - 1;
  float d0 = 1e30f, d1 = 1e30f, d2 = 1e30f;
  int i0 = 0, i1 = 0, i2 = 0;
  for (int r = half; r < 9; r += 2) {
    int ez = wz + r / 3, ey = wy + r % 3;
    int rowc = (ez * GR + ey) * GR + wx;
    int lo = s_off[rowc], hi = s_off[rowc + 3];
    for (int p = lo; p < hi; ++p) {
      float4 s = s_src[p];
      float dx = tx - s.x, dy = ty - s.y, dz = tz - s.z;
      float q = dx*dx + dy*dy + dz*dz;
      ins3(q, __float_as_int(s.w), d0, d1, d2, i0, i1, i2);
    }
  }
  pair_merge(d0, d1, d2, i0, i1, i2, 1, half);
  float clx = fminf(wx > 0 ? tx - wx * HCELL : 1e30f,
                    wx + 3 < GR ? (wx + 3) * HCELL - tx : 1e30f);
  float cly = fminf(wy > 0 ? ty - wy * HCELL : 1e30f,
                    wy + 3 < GR ? (wy + 3) * HCELL - ty : 1e30f);
  float clz = fminf(wz > 0 ? tz - wz * HCELL : 1e30f,
                    wz + 3 < GR ? (wz + 3) * HCELL - tz : 1e30f);
  float cl = fminf(clx, fminf(cly, clz));
  bool bad = d2 > cl * cl;
  if (__any(bad)) {
    if (bad) {
      d0 = d1 = d2 = 1e30f; i0 = i1 = i2 = 0;
      for (int p = half; p < NS; p += 2) {
        float4 s = s_src[p];
        float dx = tx - s.x, dy = ty - s.y, dz = tz - s.z;
        float q = dx*dx + dy*dy + dz*dz;
        ins3(q, __float_as_int(s.w), d0, d1, d2, i0, i1, i2);
      }
    }
    pair_merge(d0, d1, d2, i0, i1, i2, 1, half);
  }
  if (half == 0) {
    float r0 = fmaxf(sqrtf(d0), 1e-10f);
    float r1 = fmaxf(sqrtf(d1), 1e-10f);
    float r2 = fmaxf(sqrtf(d2), 1e-10f);
    float v0 = 1.f/r0, v1 = 1.f/r1, v2 = 1.f/r2;
    float sc = 1.f / ((v0 + v1 + v2) * (1.f + 1e-6f));
    // write at SORTED position (fused_mlp consumes sorted order)
    size_t o = ((size_t)b * NT + tseg * 128 + tpair) * 3;
    idx_out[o] = i0; idx_out[o+1] = i1; idx_out[o+2] = i2;
    w_out[o] = v0*sc; w_out[o+1] = v1*sc; w_out[o+2] = v2*sc;
  }
}

// ---------------- G = fs @ W1a  (bf16 out, no relu) ----------------
// 32-row blocks, K=256 staged once.  B-fragments 2-deep prefetched (mod-3
// rotation, fully unrolled -> static indices) with sched_barrier(0) pinning
// so the scheduler cannot sink the issues (rounds 1-3 showed it serializes
// load->MFMA otherwise).
__global__ __launch_bounds__(256, 4) void gemm_g(const float* __restrict__ fs,
    const unsigned short* __restrict__ w1at, unsigned short* __restrict__ G) {
  constexpr int LDT = 264;  // 256 + 8 pad
  __shared__ __attribute__((aligned(16))) unsigned short sA[32 * LDT];
  int tid = threadIdx.x;
  int m0 = blockIdx.x * 32;
  int wave = tid >> 6, lane = tid & 63;
  int wn = wave * 64;
  int fr = lane & 15, quad = lane >> 4;
  const unsigned short* wbase = w1at + (size_t)(wn + fr) * 256 + quad * 8;
  // stage A: 32 rows x 256 cols f32->bf16, coalesced
  #pragma unroll
  for (int i = 0; i < 4; ++i) {
    int u = tid + 256 * i;
    int r = u >> 5, k8 = (u & 31) * 8;
    const float* src = fs + (size_t)(m0 + r) * 256 + k8;
    float4 f0 = *(const float4*)src;
    float4 f1 = *(const float4*)(src + 4);
    ushortx8 o;
    o[0]=f2bf(f0.x); o[1]=f2bf(f0.y); o[2]=f2bf(f0.z); o[3]=f2bf(f0.w);
    o[4]=f2bf(f1.x); o[5]=f2bf(f1.y); o[6]=f2bf(f1.z); o[7]=f2bf(f1.w);
    *(ushortx8*)&sA[r * LDT + k8] = o;
  }
  __syncthreads();
  floatx4 zero = {0.f, 0.f, 0.f, 0.f};
  floatx4 acc[2][4];
  #pragma unroll
  for (int i = 0; i < 2; ++i)
    #pragma unroll
    for (int j = 0; j < 4; ++j) acc[i][j] = zero;
  bf16x8 wb[3][4];
  #pragma unroll
  for (int ni = 0; ni < 4; ++ni) wb[0][ni] = ldb16(wbase + (size_t)ni*16*256 + 0*32);
  #pragma unroll
  for (int ni = 0; ni < 4; ++ni) wb[1][ni] = ldb16(wbase + (size_t)ni*16*256 + 1*32);
  __builtin_amdgcn_sched_barrier(0);
  #pragma unroll
  for (int kt = 0; kt < 8; ++kt) {
    if (kt < 6) {
      #pragma unroll
      for (int ni = 0; ni < 4; ++ni)
        wb[(kt+2)%3][ni] = ldb16(wbase + (size_t)ni*16*256 + (kt+2)*32);
    }
    __builtin_amdgcn_sched_barrier(0);
    bf16x8 af[2];
    #pragma unroll
    for (int mi = 0; mi < 2; ++mi)
      af[mi] = ldb16(&sA[(mi*16 + fr)*LDT + kt*32 + quad*8]);
    #pragma unroll
    for (int mi = 0; mi < 2; ++mi)
      #pragma unroll
      for (int ni = 0; ni < 4; ++ni)
        acc[mi][ni] = __builtin_amdgcn_mfma_f32_16x16x32_bf16(
            af[mi], wb[kt%3][ni], acc[mi][ni], 0, 0, 0);
  }
  #pragma unroll
  for (int mi = 0; mi < 2; ++mi)
    #pragma unroll
    for (int ni = 0; ni < 4; ++ni)
      #pragma unroll
      for (int r = 0; r < 4; ++r) {
        int grow = m0 + mi*16 + quad*4 + r;
        int gcol = wn + ni*16 + fr;
        G[(size_t)grow * 256 + gcol] = f2bf(acc[mi][ni][r]);
      }
}

// ---------------- fused: out[orig] = relu(relu(interp + ft[orig]@W1b) @ W2) ----------------
// 64-row tile, 512 thr = 8 waves x 32-col slice (acc[4][2]).  KEY CHANGE vs
// round 3: all global loads are organized into dependency-ordered ISSUE GROUPS
// pinned with __builtin_amdgcn_sched_barrier(0) so the machine scheduler
// cannot sink them (rounds 1-3: VGPR_Count 40/60 proved it serializes loads
// to one-at-a-time otherwise).  12 interp-gather loads fly together; 16 wb2
// loads issue before the phase-1 epilogue and complete under it.
// launch_bounds(512,4): 128-VGPR cap, peak live ~115.  Numerics bit-identical.
__global__ __launch_bounds__(512, 4) void fused_mlp(const float* __restrict__ ft,
    const unsigned short* __restrict__ G, const int* __restrict__ idxb,
    const float* __restrict__ wgtb, const float4* __restrict__ stgt,
    const unsigned short* __restrict__ w1bt, const unsigned short* __restrict__ w2t,
    float* __restrict__ out) {
  constexpr int LDI = 264;
  constexpr int LDF = 136;
  __shared__ __attribute__((aligned(16))) unsigned short sI[64 * LDI];
  __shared__ __attribute__((aligned(16))) unsigned short sF[64 * LDF];
  int tid = threadIdx.x;
  int row0 = blockIdx.x * 64;   // global sorted row
  int b = row0 >> 14;
  const float4* st = stgt + ((size_t)b << 14) + (row0 & (NT - 1));
  const float* ftb = ft + (size_t)b * NT * CT;
  float* outb = out + (size_t)b * NT * NOUT;
  int wave = tid >> 6, lane = tid & 63;
  int wn = wave * 32;                 // 8 waves x 32 cols = 256
  int fr = lane & 15, quad = lane >> 4;

  // ---- A. dependency-root loads (idx/wgt for gather; sorted-row payloads for ft)
  int r = tid >> 3, seg = tid & 7;
  const int* ip = idxb + (size_t)(row0 + r) * 3;
  const float* wp = wgtb + (size_t)(row0 + r) * 3;
  int g0i = ip[0], g1i = ip[1], g2i = ip[2];
  float w0 = wp[0], w1v = wp[1], w2v = wp[2];
  int rA = tid >> 4;          // ft row for unit 0 (0..31)
  int rB = rA + 32;           // ft row for unit 1 (32..63)
  int orig0 = __float_as_int(st[rA].w);
  int orig1 = __float_as_int(st[rB].w);

  // ---- B. hoist phase-1 weights: 2x4 frags = 32 VGPR, pinned
  bf16x8 wb1[2][4];
  #pragma unroll
  for (int ni = 0; ni < 2; ++ni)
    #pragma unroll
    for (int kt = 0; kt < 4; ++kt)
      wb1[ni][kt] = ldb16(w1bt + (size_t)(wn + ni*16 + fr) * CT + kt*32 + quad*8);
  __builtin_amdgcn_sched_barrier(0);

  // ---- C. interp gather: issue ALL 12 loads (named, static) so they fly together
  const unsigned short* Gb = G + ((size_t)b << 20);
  const unsigned short* g0 = Gb + ((size_t)g0i << 8) + seg * 32;
  const unsigned short* g1 = Gb + ((size_t)g1i << 8) + seg * 32;
  const unsigned short* g2 = Gb + ((size_t)g2i << 8) + seg * 32;
  ushortx8 a0 = *(const ushortx8*)(g0 + 0);
  ushortx8 a1 = *(const ushortx8*)(g0 + 8);
  ushortx8 a2 = *(const ushortx8*)(g0 + 16);
  ushortx8 a3 = *(const ushortx8*)(g0 + 24);
  ushortx8 c0 = *(const ushortx8*)(g1 + 0);
  ushortx8 c1 = *(const ushortx8*)(g1 + 8);
  ushortx8 c2 = *(const ushortx8*)(g1 + 16);
  ushortx8 c3 = *(const ushortx8*)(g1 + 24);
  ushortx8 e0 = *(const ushortx8*)(g2 + 0);
  ushortx8 e1 = *(const ushortx8*)(g2 + 8);
  ushortx8 e2 = *(const ushortx8*)(g2 + 16);
  ushortx8 e3 = *(const ushortx8*)(g2 + 24);

  // ---- D. ft tile loads (rows via orig), issued before any combine VALU
  int k8 = (tid & 15) * 8;
  const float* srcA = ftb + (size_t)orig0 * CT + k8;
  const float* srcB = ftb + (size_t)orig1 * CT + k8;
  float4 fa0 = *(const float4*)srcA;
  float4 fa1 = *(const float4*)(srcA + 4);
  float4 fb0 = *(const float4*)srcB;
  float4 fb1 = *(const float4*)(srcB + 4);
  __builtin_amdgcn_sched_barrier(0);

  // ---- E. interp combine + LDS write (loads above all in flight / done)
  {
    unsigned short* dst = &sI[r * LDI + seg * 32];
    *(ushortx8*)(dst + 0)  = wsum8(a0, c0, e0, w0, w1v, w2v);
    *(ushortx8*)(dst + 8)  = wsum8(a1, c1, e1, w0, w1v, w2v);
    *(ushortx8*)(dst + 16) = wsum8(a2, c2, e2, w0, w1v, w2v);
    *(ushortx8*)(dst + 24) = wsum8(a3, c3, e3, w0, w1v, w2v);
  }
  // ---- F. ft cvt + LDS write
  {
    ushortx8 o;
    o[0]=f2bf(fa0.x); o[1]=f2bf(fa0.y); o[2]=f2bf(fa0.z); o[3]=f2bf(fa0.w);
    o[4]=f2bf(fa1.x); o[5]=f2bf(fa1.y); o[6]=f2bf(fa1.z); o[7]=f2bf(fa1.w);
    *(ushortx8*)&sF[rA * LDF + k8] = o;
    ushortx8 p;
    p[0]=f2bf(fb0.x); p[1]=f2bf(fb0.y); p[2]=f2bf(fb0.z); p[3]=f2bf(fb0.w);
    p[4]=f2bf(fb1.x); p[5]=f2bf(fb1.y); p[6]=f2bf(fb1.z); p[7]=f2bf(fb1.w);
    *(ushortx8*)&sF[rB * LDF + k8] = p;
  }
  __syncthreads();

  floatx4 zero = {0.f, 0.f, 0.f, 0.f};
  floatx4 acc[4][2];
  #pragma unroll
  for (int i = 0; i < 4; ++i)
    #pragma unroll
    for (int j = 0; j < 2; ++j) acc[i][j] = zero;

  // ---- phase 1: ft @ W1b (K=128); B in registers, A from LDS
  #pragma unroll
  for (int kt = 0; kt < 4; ++kt) {
    bf16x8 af[4];
    #pragma unroll
    for (int mi = 0; mi < 4; ++mi)
      af[mi] = ldb16(&sF[(mi*16 + fr)*LDF + kt*32 + quad*8]);
    #pragma unroll
    for (int mi = 0; mi < 4; ++mi)
      #pragma unroll
      for (int ni = 0; ni < 2; ++ni)
        acc[mi][ni] = __builtin_amdgcn_mfma_f32_16x16x32_bf16(
            af[mi], wb1[ni][kt], acc[mi][ni], 0, 0, 0);
  }

  // ---- G. issue ALL phase-2 weight loads (16 frags = 64 VGPR), pinned;
  //      latency completes under the epilogue + barrier below.
  bf16x8 wb2[2][8];
  #pragma unroll
  for (int ni = 0; ni < 2; ++ni)
    #pragma unroll
    for (int kt = 0; kt < 8; ++kt)
      wb2[ni][kt] = ldb16(w2t + (size_t)(wn + ni*16 + fr) * NOUT + kt*32 + quad*8);
  __builtin_amdgcn_sched_barrier(0);

  // ---- phase-1 epilogue: T = relu(acc + interp) bf16, in-place in sI (own cells)
  #pragma unroll
  for (int mi = 0; mi < 4; ++mi)
    #pragma unroll
    for (int ni = 0; ni < 2; ++ni)
      #pragma unroll
      for (int rr = 0; rr < 4; ++rr) {
        int lr = mi*16 + quad*4 + rr;
        int lc = wn + ni*16 + fr;
        float v = acc[mi][ni][rr] + bf2f(sI[lr * LDI + lc]);
        sI[lr * LDI + lc] = f2bf(fmaxf(v, 0.f));
      }
  __syncthreads();

  // ---- phase 2: T @ W2 (K=256); B in registers, A from LDS, no barriers
  #pragma unroll
  for (int i = 0; i < 4; ++i)
    #pragma unroll
    for (int j = 0; j < 2; ++j) acc[i][j] = zero;
  #pragma unroll
  for (int kt = 0; kt < 8; ++kt) {
    bf16x8 af[4];
    #pragma unroll
    for (int mi = 0; mi < 4; ++mi)
      af[mi] = ldb16(&sI[(mi*16 + fr)*LDI + kt*32 + quad*8]);
    #pragma unroll
    for (int mi = 0; mi < 4; ++mi)
      #pragma unroll
      for (int ni = 0; ni < 2; ++ni)
        acc[mi][ni] = __builtin_amdgcn_mfma_f32_16x16x32_bf16(
            af[mi], wb2[ni][kt], acc[mi][ni], 0, 0, 0);
  }
  // ---- out epilogue: scatter rows back to original positions
  #pragma unroll
  for (int mi = 0; mi < 4; ++mi)
    #pragma unroll
    for (int rr = 0; rr < 4; ++rr) {
      int lr = mi*16 + quad*4 + rr;
      int orig = __float_as_int(st[lr].w);
      float* orow = outb + (size_t)orig * NOUT;
      #pragma unroll
      for (int ni = 0; ni < 2; ++ni)
        orow[wn + ni*16 + fr] = fmaxf(acc[mi][ni][rr], 0.f);
    }
}

extern "C" void kernel_launch(void* const* d_in, const int* in_sizes, int n_in,
                              void* d_out, int out_size, void* d_ws, size_t ws_size,
                              hipStream_t stream) {
  (void)in_sizes; (void)n_in; (void)out_size; (void)ws_size;
  const float* xyzt = (const float*)d_in[0];
  const float* xyzs = (const float*)d_in[1];
  const float* ft   = (const float*)d_in[2];
  const float* fs   = (const float*)d_in[3];
  const float* w1   = (const float*)d_in[4];
  const float* w2   = (const float*)d_in[5];

  char* p = (char*)d_ws;
  unsigned short* w1at = (unsigned short*)p; p += (size_t)256*256*2;
  unsigned short* w1bt = (unsigned short*)p; p += (size_t)256*128*2;
  unsigned short* w2t  = (unsigned short*)p; p += (size_t)256*256*2;
  int*   idxb = (int*)p;   p += (size_t)MTOT*3*4;
  float* wgtb = (float*)p; p += (size_t)MTOT*3*4;
  unsigned short* G = (unsigned short*)p; p += (size_t)BS*NS*NOUT*2;
  float4* bsrc = (float4*)p; p += (size_t)BS*NS*16;
  float4* stgt = (float4*)p; p += (size_t)BS*NT*16;
  int*    soff = (int*)p;

  hipLaunchKernelGGL(prep_kernel, dim3(8 + 64), dim3(1024), 0, stream,
                     xyzs, xyzt, w1, w2, bsrc, soff, stgt, w1at, w1bt, w2t);
  hipLaunchKernelGGL(nn_kernel, dim3(512), dim3(256), 0, stream, stgt, bsrc, soff, idxb, wgtb);
  hipLaunchKernelGGL(gemm_g, dim3(BS*NS/32), dim3(256), 0, stream, fs, w1at, G);
  hipLaunchKernelGGL(fused_mlp, dim3(MTOT/64), dim3(512), 0, stream,
                     ft, G, idxb, wgtb, stgt, w1bt, w2t, (float*)d_out);
}